// Round 7
// baseline (314.238 us; speedup 1.0000x reference)
//
#include <hip/hip_runtime.h>
#include <hip/hip_bf16.h>

#define N_NODES 8192
#define BGRAPH 8
#define NPG 1024
#define DIM 256
#define NH 8
#define DHEAD 32
#define NLAYERS 2
#define INC 128
#define OUTD 64
#define NEDGE 262144
#define DFF 512
#define EPS 1e-5f

typedef __attribute__((ext_vector_type(4))) float f32x4;
typedef __attribute__((ext_vector_type(8))) short s16x8;
typedef __attribute__((ext_vector_type(4))) ushort u16x4;

__device__ __forceinline__ float b2f(ushort u){
  unsigned v = ((unsigned)u) << 16;
  return __builtin_bit_cast(float, v);
}
__device__ __forceinline__ ushort f2b(float f){
  unsigned u = __builtin_bit_cast(unsigned, f);
  u += 0x7fffu + ((u >> 16) & 1u);
  return (ushort)(u >> 16);
}
__device__ __forceinline__ ushort f2b_trunc(float f){
  return (ushort)(__builtin_bit_cast(unsigned, f) >> 16);
}
// async global->LDS, 16B per lane; lds base must be wave-uniform (HW adds lane*16)
__device__ __forceinline__ void gload16(const void* g, void* l){
  __builtin_amdgcn_global_load_lds(
    (const __attribute__((address_space(1))) void*)g,
    (__attribute__((address_space(3))) void*)l,
    16, 0, 0);
}

// ---------------------------------------------------------------------------
// Graph setup
// ---------------------------------------------------------------------------
__global__ void k_count_deg(const int* __restrict__ dst, int* __restrict__ deg){
  int i = blockIdx.x*blockDim.x + threadIdx.x;
  int stride = gridDim.x*blockDim.x;
  for(; i<NEDGE; i+=stride) atomicAdd(&deg[dst[i]], 1);
}
__global__ void k_scan(const int* __restrict__ deg, int* __restrict__ offs,
                       float* __restrict__ inv_deg){
  __shared__ int s[1024];
  int t = threadIdx.x;
  int base = t*8;
  int loc[8]; int acc=0;
  #pragma unroll
  for(int j=0;j<8;j++){
    int dv = deg[base+j];
    inv_deg[base+j] = 1.0f/(float)(dv>0?dv:1);
    loc[j]=acc; acc += dv;
  }
  s[t]=acc;
  __syncthreads();
  for(int d=1; d<1024; d<<=1){
    int v = (t>=d)? s[t-d] : 0;
    __syncthreads();
    if(t>=d) s[t]+=v;
    __syncthreads();
  }
  int pre = (t>0)? s[t-1] : 0;
  #pragma unroll
  for(int j=0;j<8;j++) offs[base+j] = pre + loc[j];
  if(t==1023) offs[N_NODES] = s[1023];
}
__global__ void k_fill_csr(const int* __restrict__ src, const int* __restrict__ dst,
                           const int* __restrict__ offs, int* __restrict__ cursor,
                           int* __restrict__ csr){
  int i = blockIdx.x*blockDim.x + threadIdx.x;
  int stride = gridDim.x*blockDim.x;
  for(; i<NEDGE; i+=stride){
    int d = dst[i];
    int p = atomicAdd(&cursor[d], 1);
    csr[offs[d]+p] = src[i];
  }
}

// mean-aggregate: one node per WAVE, lane owns 4 channels (8B loads),
// neighbor loop unrolled x4. No LDS/barriers.
__global__ __launch_bounds__(256) void k_aggregate(ushort* __restrict__ hwb,
    const int* __restrict__ offs, const int* __restrict__ csr,
    const float* __restrict__ inv_deg){
  int n = blockIdx.x*4 + (threadIdx.x>>6);
  int lane = threadIdx.x & 63;
  int beg = offs[n], end = offs[n+1];
  f32x4 a0 = {0,0,0,0}, a1 = {0,0,0,0}, a2 = {0,0,0,0}, a3 = {0,0,0,0};
  int i = beg;
  for(; i+4<=end; i+=4){
    int j0=csr[i], j1=csr[i+1], j2=csr[i+2], j3=csr[i+3];
    u16x4 v0 = *(const u16x4*)(hwb + (size_t)j0*512 + 256 + lane*4);
    u16x4 v1 = *(const u16x4*)(hwb + (size_t)j1*512 + 256 + lane*4);
    u16x4 v2 = *(const u16x4*)(hwb + (size_t)j2*512 + 256 + lane*4);
    u16x4 v3 = *(const u16x4*)(hwb + (size_t)j3*512 + 256 + lane*4);
    #pragma unroll
    for(int c=0;c<4;c++){ a0[c]+=b2f(v0[c]); a1[c]+=b2f(v1[c]);
                          a2[c]+=b2f(v2[c]); a3[c]+=b2f(v3[c]); }
  }
  for(; i<end; ++i){
    int j0=csr[i];
    u16x4 v0 = *(const u16x4*)(hwb + (size_t)j0*512 + 256 + lane*4);
    #pragma unroll
    for(int c=0;c<4;c++) a0[c]+=b2f(v0[c]);
  }
  float inv = inv_deg[n];
  u16x4 outv;
  #pragma unroll
  for(int c=0;c<4;c++) outv[c] = f2b((a0[c]+a1[c]+a2[c]+a3[c])*inv);
  *(u16x4*)(hwb + (size_t)n*512 + lane*4) = outv;
}

// ---------------------------------------------------------------------------
// bf16 MFMA GEMM, 3-buffer depth-2 prefetch, counted vmcnt (T3+T4).
// C[M,Nc] = A[M,K] @ W[Nc,K]^T (+bias)(+resid f32|bf16) -> f32/bf16 (+BN stats)
// 64x64 tile, BK=64, 256 thr = 4 waves (2x2), each wave 32x32 (2x2 frags)
// ---------------------------------------------------------------------------
#define STAGE_AB(t, buf) do{ \
    int kt_ = (t)*64; \
    _Pragma("unroll") \
    for(int it=0; it<2; ++it){ \
      int c = (wave*2+it)*64 + lane; \
      int row = c >> 3, q = c & 7; \
      int qs = q ^ (row & 7); \
      gload16(A + (size_t)(bm+row)*lda + kt_ + qs*8, (char*)As + (buf)*8192 + (wave*2+it)*1024); \
      gload16(W + (size_t)(bn+row)*K   + kt_ + qs*8, (char*)Bs + (buf)*8192 + (wave*2+it)*1024); \
    } \
  }while(0)

template<bool RELU, bool RESID, bool RESIDB, bool BIAS, bool WF32, bool WBF, bool STATS>
__global__ __launch_bounds__(256) void k_mm(const ushort* __restrict__ A,
    const ushort* __restrict__ W, const float* __restrict__ bias,
    const float* __restrict__ resid, const ushort* __restrict__ residb,
    float* __restrict__ Cf, ushort* __restrict__ Cb,
    float* __restrict__ gS, float* __restrict__ gQ,
    int M, int Nc, int K, int lda, int ldcb)
{
  __shared__ ushort As[3*64*64];   // 24KB (3 bufs)
  __shared__ ushort Bs[3*64*64];   // 24KB
  __shared__ float sredS[64];
  __shared__ float sredQ[64];
  const int tid = threadIdx.x;
  const int lane = tid & 63, wave = tid >> 6;
  const int l15 = lane & 15, l4 = lane >> 4;
  const int bm = blockIdx.y*64, bn = blockIdx.x*64;
  const int wr = wave >> 1, wc = wave & 1;
  f32x4 acc[2][2] = {};
  const int nt = K >> 6;

  STAGE_AB(0, 0);
  if(nt > 1) STAGE_AB(1, 1);

  for(int t=0; t<nt; ++t){
    int cb = t % 3;
    if(t+2 < nt){
      STAGE_AB(t+2, (t+2)%3);
      asm volatile("s_waitcnt vmcnt(8)" ::: "memory");   // stage(t) drained
    } else if(t+1 < nt){
      asm volatile("s_waitcnt vmcnt(4)" ::: "memory");
    } else {
      asm volatile("s_waitcnt vmcnt(0)" ::: "memory");
    }
    __builtin_amdgcn_s_barrier();
    #pragma unroll
    for(int kk=0; kk<2; ++kk){
      s16x8 af[2], bfr[2];
      #pragma unroll
      for(int mi=0; mi<2; ++mi){
        int row = wr*32 + mi*16 + l15;
        int col = (kk*64 + l4*16) ^ ((row & 7) << 4);
        af[mi] = *(const s16x8*)((const char*)As + cb*8192 + row*128 + col);
      }
      #pragma unroll
      for(int nj=0; nj<2; ++nj){
        int row = wc*32 + nj*16 + l15;
        int col = (kk*64 + l4*16) ^ ((row & 7) << 4);
        bfr[nj] = *(const s16x8*)((const char*)Bs + cb*8192 + row*128 + col);
      }
      #pragma unroll
      for(int mi=0; mi<2; ++mi)
        #pragma unroll
        for(int nj=0; nj<2; ++nj)
          acc[mi][nj] = __builtin_amdgcn_mfma_f32_16x16x32_bf16(af[mi], bfr[nj], acc[mi][nj], 0,0,0);
    }
    asm volatile("s_waitcnt lgkmcnt(0)" ::: "memory");
    __builtin_amdgcn_s_barrier();
  }

  float sloc[2] = {0.f,0.f}, qloc[2] = {0.f,0.f};
  #pragma unroll
  for(int mi=0; mi<2; ++mi){
    #pragma unroll
    for(int nj=0; nj<2; ++nj){
      int col = bn + wc*32 + nj*16 + l15;
      float bv = BIAS ? bias[col] : 0.f;
      #pragma unroll
      for(int r=0; r<4; ++r){
        int row = bm + wr*32 + mi*16 + l4*4 + r;
        size_t off = (size_t)row*Nc + col;
        float v = acc[mi][nj][r] + bv;
        if(RESID)  v += resid[off];
        if(RESIDB) v += b2f(residb[off]);
        if(RELU)   v = fmaxf(v, 0.f);
        if(WF32)   Cf[off] = v;
        if(WBF)    Cb[(size_t)row*ldcb + col] = f2b(v);
        if(STATS){ sloc[nj] += v; qloc[nj] += v*v; }
      }
    }
  }
  if(STATS){
    if(tid < 64){ sredS[tid]=0.f; sredQ[tid]=0.f; }
    __syncthreads();
    int c0 = wc*32 + l15;
    atomicAdd(&sredS[c0],    sloc[0]); atomicAdd(&sredQ[c0],    qloc[0]);
    atomicAdd(&sredS[c0+16], sloc[1]); atomicAdd(&sredQ[c0+16], qloc[1]);
    __syncthreads();
    if(tid < 64){
      atomicAdd(&gS[bn+tid], sredS[tid]);
      atomicAdd(&gQ[bn+tid], sredQ[tid]);
    }
  }
}

// ---------------------------------------------------------------------------
// MFMA flash attention: double-buffered K (gload16) + V (reg->LDS, T14 split),
// merged 64-key softmax, exp2 domain, defer-max, setprio around MFMA.
// ---------------------------------------------------------------------------
__global__ __launch_bounds__(256) void k_attn(const ushort* __restrict__ qkv,
                                              ushort* __restrict__ attnO)
{
  __shared__ ushort Ks[2][64*32];   // 2 x 4KB
  __shared__ ushort Vt[2][32*64];   // 2 x 4KB
  const int tid = threadIdx.x, lane = tid & 63, wave = tid >> 6;
  const int l15 = lane & 15, g = lane >> 4;
  int bid = blockIdx.x;
  int qc = bid & 15;
  int h  = (bid >> 4) & 7;
  int bg = bid >> 7;
  const int nb = bg*NPG + qc*64 + wave*16;
  const int kb = bg*NPG;

  // K staging address (constant across stages except st)
  const int rho = tid >> 2, qq = tid & 3;
  const int grp = rho >> 5, r32 = rho & 31;
  const int tt = r32 >> 4, wi = r32 & 15;
  const int jperm = grp*32 + (wi >> 2)*8 + tt*4 + (wi & 3);
  const int qs = qq ^ ((rho >> 1) & 3);

  // Q frag (B operand); fold 1/sqrt(32)*log2(e): scores in log2 domain
  s16x8 qf = *(const s16x8*)(qkv + (size_t)(nb + l15)*768 + h*32 + g*8);
  {
    const float scale2 = 0.2550370703637335f;
    #pragma unroll
    for(int i=0;i<8;i++) qf[i] = (short)f2b(b2f((ushort)qf[i]) * scale2);
  }
  f32x4 o0 = {0.f,0.f,0.f,0.f}, o1 = {0.f,0.f,0.f,0.f};
  float mrun = -1e30f, lrun = 0.f;

  // prologue: stage K(0), load V(0) into regs
  gload16(qkv + (size_t)(kb + jperm)*768 + 256 + h*32 + qs*8, (char*)Ks[0] + wave*1024);
  s16x8 vcur = *(const s16x8*)(qkv + (size_t)(kb + lane)*768 + 512 + h*32 + wave*8);

  for(int st=0; st<16; ++st){
    int buf = st & 1;
    // write V(st) regs -> Vt[buf] (compiler's wait on vcur also drains K(st): in-order vmcnt)
    #pragma unroll
    for(int i=0;i<8;i++){
      int d = wave*8 + i;
      Vt[buf][d*64 + (lane ^ (i<<3))] = (ushort)vcur[i];
    }
    s16x8 vnext = vcur;
    if(st+1 < 16){
      gload16(qkv + (size_t)(kb + (st+1)*64 + jperm)*768 + 256 + h*32 + qs*8,
              (char*)Ks[buf^1] + wave*1024);
      vnext = *(const s16x8*)(qkv + (size_t)(kb + (st+1)*64 + lane)*768 + 512 + h*32 + wave*8);
      asm volatile("s_waitcnt vmcnt(2) lgkmcnt(0)" ::: "memory");
    } else {
      asm volatile("s_waitcnt vmcnt(0) lgkmcnt(0)" ::: "memory");
    }
    __builtin_amdgcn_s_barrier();

    // QK^T: 4 score frags over 64 keys (swapped operands)
    f32x4 sc[4];
    __builtin_amdgcn_s_setprio(1);
    #pragma unroll
    for(int q4=0; q4<4; ++q4){
      int r0 = q4*16 + l15;
      s16x8 kf = *(const s16x8*)((const char*)Ks[buf] + r0*64 + ((g*16) ^ (((r0>>1)&3)<<4)));
      f32x4 z = {0.f,0.f,0.f,0.f};
      sc[q4] = __builtin_amdgcn_mfma_f32_16x16x32_bf16(kf, qf, z, 0,0,0);
    }
    __builtin_amdgcn_s_setprio(0);

    float smax = -1e30f;
    #pragma unroll
    for(int q4=0; q4<4; ++q4)
      #pragma unroll
      for(int r=0; r<4; ++r) smax = fmaxf(smax, sc[q4][r]);
    smax = fmaxf(smax, __shfl_xor(smax, 16));
    smax = fmaxf(smax, __shfl_xor(smax, 32));

    if(!__all((int)(smax <= mrun + 8.0f))){
      float mnew = fmaxf(mrun, smax);
      float alpha = exp2f(mrun - mnew);
      lrun *= alpha;
      #pragma unroll
      for(int r=0;r<4;r++){
        float ar = __shfl(alpha, (lane & 48) | (g*4 + r), 64);
        o0[r] *= ar; o1[r] *= ar;
      }
      mrun = mnew;
    }

    float p[16];
    float ps = 0.f;
    #pragma unroll
    for(int q4=0; q4<4; ++q4)
      #pragma unroll
      for(int r=0; r<4; ++r){
        float pv = exp2f(sc[q4][r] - mrun);
        p[q4*4+r] = pv; ps += pv;
      }
    ps += __shfl_xor(ps, 16);
    ps += __shfl_xor(ps, 32);
    lrun += ps;

    s16x8 pa0, pa1;
    #pragma unroll
    for(int i=0;i<8;i++){ pa0[i] = (short)f2b_trunc(p[i]); pa1[i] = (short)f2b_trunc(p[8+i]); }

    int colb0 = g*16, colb1 = 64 + g*16;
    int d0 = l15, d1 = l15 + 16;
    s16x8 v00 = *(const s16x8*)((const char*)Vt[buf] + d0*128 + (colb0 ^ ((d0&7)<<4)));
    s16x8 v01 = *(const s16x8*)((const char*)Vt[buf] + d1*128 + (colb0 ^ ((d1&7)<<4)));
    s16x8 v10 = *(const s16x8*)((const char*)Vt[buf] + d0*128 + (colb1 ^ ((d0&7)<<4)));
    s16x8 v11 = *(const s16x8*)((const char*)Vt[buf] + d1*128 + (colb1 ^ ((d1&7)<<4)));
    __builtin_amdgcn_s_setprio(1);
    o0 = __builtin_amdgcn_mfma_f32_16x16x32_bf16(pa0, v00, o0, 0,0,0);
    o1 = __builtin_amdgcn_mfma_f32_16x16x32_bf16(pa0, v01, o1, 0,0,0);
    o0 = __builtin_amdgcn_mfma_f32_16x16x32_bf16(pa1, v10, o0, 0,0,0);
    o1 = __builtin_amdgcn_mfma_f32_16x16x32_bf16(pa1, v11, o1, 0,0,0);
    __builtin_amdgcn_s_setprio(0);

    asm volatile("s_waitcnt lgkmcnt(0)" ::: "memory");
    __builtin_amdgcn_s_barrier();
    vcur = vnext;
  }
  float inv = 1.0f/lrun;
  #pragma unroll
  for(int r=0;r<4;r++){
    int q2 = g*4 + r;
    float ir = __shfl(inv, (lane & 48) | q2, 64);
    size_t nrow = (size_t)(nb + q2)*DIM + h*32;
    attnO[nrow + l15]      = f2b(o0[r]*ir);
    attnO[nrow + 16 + l15] = f2b(o1[r]*ir);
  }
}

// ---------------------------------------------------------------------------
// Fused BN applies. slot layout per layer: [s1|q1|s2|q2|s3|q3] x 256 floats
// ---------------------------------------------------------------------------
__global__ __launch_bounds__(256) void k_apply12(const float* __restrict__ locC,
    const float* __restrict__ globC, const float* __restrict__ slot,
    const float* __restrict__ n1w, const float* __restrict__ n1b,
    const float* __restrict__ n2w, const float* __restrict__ n2b,
    ushort* __restrict__ combB){
  int d = threadIdx.x;
  size_t i = (size_t)blockIdx.x*DIM + d;
  const float invn = 1.0f/N_NODES;
  float m1 = slot[d]*invn,     v1 = slot[256+d]*invn - m1*m1;
  float m2 = slot[512+d]*invn, v2 = slot[768+d]*invn - m2*m2;
  float rs1 = rsqrtf(v1+EPS), rs2 = rsqrtf(v2+EPS);
  float y1 = (locC[i]-m1)*rs1*n1w[d] + n1b[d];
  float y2 = (globC[i]-m2)*rs2*n2w[d] + n2b[d];
  combB[i] = f2b(y1 + y2);
}

// BN3 + outer BN + relu + residual (closed form: mean(BN3)=b3, var(BN3)=(rs*w3)^2*var)
__global__ __launch_bounds__(256) void k_apply3o(const float* __restrict__ x,
    const float* __restrict__ slot, const float* __restrict__ n3w,
    const float* __restrict__ n3b, const float* __restrict__ bw,
    const float* __restrict__ bb, float* __restrict__ H,
    ushort* __restrict__ hwbR){
  int d = threadIdx.x;
  size_t i = (size_t)blockIdx.x*DIM + d;
  const float invn = 1.0f/N_NODES;
  float m   = slot[1024+d]*invn;
  float var = slot[1280+d]*invn - m*m;
  float rs  = rsqrtf(var+EPS);
  float gch = rs*n3w[d];
  float rso = rsqrtf(gch*gch*var + EPS);
  float yo = (x[i]-m)*gch*rso*bw[d] + bb[d];
  float h = H[i] + fmaxf(yo, 0.f);
  H[i] = h;
  hwbR[(size_t)blockIdx.x*512 + d] = f2b(h);
}

// ---------------------------------------------------------------------------
// cast x + weights f32 -> bf16 ; SAGE weights fused as [wl|wr] along K
// ---------------------------------------------------------------------------
#define CX  1048576
#define CWI (CX+32768)
#define CSW (CWI+262144)
#define CIW (CSW+393216)
#define COW (CIW+131072)
#define CW1 (COW+262144)
#define CW2 (CW1+262144)   // total 2392064
__global__ void k_cast_all(const float* __restrict__ x, const float* __restrict__ w_in,
    const float* __restrict__ wl, const float* __restrict__ wr,
    const float* __restrict__ iw, const float* __restrict__ ow,
    const float* __restrict__ w1, const float* __restrict__ w2,
    ushort* __restrict__ dst){
  int i = blockIdx.x*256 + threadIdx.x;
  float val;
  if(i < CX)       val = x[i];
  else if(i < CWI) val = w_in[i-CX];
  else if(i < CSW){
    int j = i - CWI;
    int l = j >> 17, r = (j >> 9) & 255, k = j & 511;
    val = (k < 256) ? wl[(l<<16) + (r<<8) + k] : wr[(l<<16) + (r<<8) + (k-256)];
  }
  else if(i < CIW) val = iw[i-CSW];
  else if(i < COW) val = ow[i-CIW];
  else if(i < CW1) val = w1[i-COW];
  else             val = w2[i-CW1];
  dst[i] = f2b(val);
}

// ---------------------------------------------------------------------------
// Pooling + head
// ---------------------------------------------------------------------------
__global__ void k_pool(const float* __restrict__ h, float* __restrict__ pooled){
  int b = blockIdx.x, c = blockIdx.y, d = threadIdx.x;
  int r0 = c*64;
  float s=0.f;
  for(int i=0;i<64;i++) s += h[(size_t)(b*NPG + r0 + i)*DIM + d];
  atomicAdd(&pooled[b*DIM+d], s*(1.0f/NPG));
}
__global__ void k_out(const float* __restrict__ pooled, const float* __restrict__ w_out,
                      const float* __restrict__ b_out, float* __restrict__ out){
  int t = threadIdx.x;
  if(t >= BGRAPH*OUTD) return;
  int b = t/OUTD, oc = t%OUTD;
  float s = b_out[oc];
  for(int k=0;k<DIM;k++) s += pooled[b*DIM+k]*w_out[oc*DIM+k];
  out[t] = s;
}

// ---------------------------------------------------------------------------
// Orchestration
// ---------------------------------------------------------------------------
extern "C" void kernel_launch(void* const* d_in, const int* in_sizes, int n_in,
                              void* d_out, int out_size, void* d_ws, size_t ws_size,
                              hipStream_t stream) {
  const float* x       = (const float*)d_in[0];
  const int*   edge    = (const int*)d_in[1];
  const float* w_in    = (const float*)d_in[3];
  const float* b_in    = (const float*)d_in[4];
  const float* sage_wl = (const float*)d_in[5];
  const float* sage_bl = (const float*)d_in[6];
  const float* sage_wr = (const float*)d_in[7];
  const float* attn_iw = (const float*)d_in[8];
  const float* attn_ib = (const float*)d_in[9];
  const float* attn_ow = (const float*)d_in[10];
  const float* attn_ob = (const float*)d_in[11];
  const float* n1_w = (const float*)d_in[12];
  const float* n1_b = (const float*)d_in[13];
  const float* n2_w = (const float*)d_in[14];
  const float* n2_b = (const float*)d_in[15];
  const float* n3_w = (const float*)d_in[16];
  const float* n3_b = (const float*)d_in[17];
  const float* mlp_w1 = (const float*)d_in[18];
  const float* mlp_b1 = (const float*)d_in[19];
  const float* mlp_w2 = (const float*)d_in[20];
  const float* mlp_b2 = (const float*)d_in[21];
  const float* bn_w = (const float*)d_in[22];
  const float* bn_b = (const float*)d_in[23];
  const float* w_out = (const float*)d_in[24];
  const float* b_out = (const float*)d_in[25];

  const size_t ND = (size_t)N_NODES*DIM;        // 2,097,152
  float* ws    = (float*)d_ws;
  float* H     = ws;
  float* locC  = ws + ND;
  float* globC = ws + 2*ND;
  ushort* wsb   = (ushort*)(ws + 3*ND);
  ushort* hwb   = wsb;             // [N][512] : [agg | H] bf16
  ushort* qkvb  = wsb + 2*ND;      // 3*ND
  ushort* attnOb= wsb + 5*ND;
  ushort* combb = wsb + 6*ND;
  ushort* hidb  = wsb + 7*ND;      // [N][512]
  ushort* castb = wsb + 9*ND;
  ushort* xb     = castb;
  ushort* w_in_b = castb + CX;
  ushort* sageWb = castb + CWI;
  ushort* iw_b   = castb + CSW;
  ushort* ow_b   = castb + CIW;
  ushort* w1_b   = castb + COW;
  ushort* w2_b   = castb + CW1;
  float* mf      = (float*)(castb + CW2);
  float* inv_deg = mf;
  float* bnslots = mf + 8192;
  float* pooled  = bnslots + 3072;
  int* deg    = (int*)(pooled + 2048);
  int* cursor = deg + N_NODES;
  int* offs   = cursor + N_NODES;
  int* csr    = offs + N_NODES + 8;

  const int* esrc = edge;
  const int* edst = edge + NEDGE;

  hipMemsetAsync(bnslots, 0, (3072+2048)*sizeof(float) + 2*N_NODES*sizeof(int), stream);

  k_count_deg<<<512,256,0,stream>>>(edst, deg);
  k_scan<<<1,1024,0,stream>>>(deg, offs, inv_deg);
  k_fill_csr<<<512,256,0,stream>>>(esrc, edst, offs, cursor, csr);
  k_cast_all<<<CW2/256,256,0,stream>>>(x, w_in, sage_wl, sage_wr, attn_iw,
      attn_ow, mlp_w1, mlp_w2, castb);

  // in_proj: H(f32) + hwb right half(bf16) = x @ w_in^T + b_in
  k_mm<false,false,false,true,true,true,false><<<dim3(4,128),256,0,stream>>>(
      xb, w_in_b, b_in, nullptr, nullptr, H, hwb+256, nullptr, nullptr,
      N_NODES, DIM, INC, INC, 512);

  for(int l=0; l<NLAYERS; ++l){
    const ushort* swb = sageWb + (size_t)l*131072;   // [256][512] = [wl|wr]
    const ushort* iwb = iw_b + (size_t)l*196608;
    const ushort* owb = ow_b + (size_t)l*65536;
    const ushort* w1b = w1_b + (size_t)l*131072;
    const ushort* w2b = w2_b + (size_t)l*131072;
    float* slot = bnslots + (size_t)l*1536;

    // SAGE fused GEMM over [agg|H], K=512, +H resid, BN1 stats
    k_aggregate<<<N_NODES/4,256,0,stream>>>(hwb, offs, csr, inv_deg);
    k_mm<false,true,false,true,true,false,true><<<dim3(4,128),256,0,stream>>>(
        hwb, swb, sage_bl + l*DIM, H, nullptr, locC, nullptr, slot, slot+256,
        N_NODES, DIM, 512, 512, 0);

    // attention: qkv from H (right half of hwb, lda=512), flash, out-proj
    k_mm<false,false,false,true,false,true,false><<<dim3(12,128),256,0,stream>>>(
        hwb+256, iwb, attn_ib + l*3*DIM, nullptr, nullptr, nullptr, qkvb,
        nullptr, nullptr, N_NODES, 3*DIM, DIM, 512, 768);
    k_attn<<<1024,256,0,stream>>>(qkvb, attnOb);
    k_mm<false,true,false,true,true,false,true><<<dim3(4,128),256,0,stream>>>(
        attnOb, owb, attn_ob + l*DIM, H, nullptr, globC, nullptr, slot+512, slot+768,
        N_NODES, DIM, DIM, DIM, 0);

    // comb = BN1(loc) + BN2(glob)  (bf16 only)
    k_apply12<<<N_NODES,256,0,stream>>>(locC, globC, slot,
        n1_w + l*DIM, n1_b + l*DIM, n2_w + l*DIM, n2_b + l*DIM, combb);

    // MLP: hid = relu(comb@w1^T+b1) ; out2 = comb + hid@w2^T + b2 (+BN3 stats)
    k_mm<true,false,false,true,false,true,false><<<dim3(8,128),256,0,stream>>>(
        combb, w1b, mlp_b1 + l*DFF, nullptr, nullptr, nullptr, hidb,
        nullptr, nullptr, N_NODES, DFF, DIM, DIM, 512);
    k_mm<false,false,true,true,true,false,true><<<dim3(4,128),256,0,stream>>>(
        hidb, w2b, mlp_b2 + l*DIM, nullptr, combb, globC, nullptr,
        slot+1024, slot+1280, N_NODES, DIM, 512, 512, 0);

    // BN3 + outer BN + relu + residual -> H, hwb right half
    k_apply3o<<<N_NODES,256,0,stream>>>(globC, slot, n3_w + l*DIM, n3_b + l*DIM,
        bn_w + l*DIM, bn_b + l*DIM, H, hwb+256);
  }

  k_pool<<<dim3(BGRAPH, NPG/64),256,0,stream>>>(H, pooled);
  k_out<<<1,512,0,stream>>>(pooled, w_out, b_out, (float*)d_out);
}